// Round 4
// baseline (559.662 us; speedup 1.0000x reference)
//
#include <hip/hip_runtime.h>

#define B_N 1024
#define X_N 1024
#define Y_N 16384
#define Z_N 1000
#define GK  2048
#define MARGIN 0.017f

// output float offsets
#define OFF_ACT      0
#define OFF_MAXRESP  1
#define OFF_WX       1025
#define OFF_WZ       16778241
#define OFF_U        33162241
#define OFF_THR      49546241
#define OFF_AGE      49562625
#define OFF_ZAGE     49579009

// scratch placed inside not-yet-written d_out regions (16B aligned byte offsets)
#define SCR_B_BYTES    4112ull       /* Bb bf16 64MB, in OFF_WX region */
#define SCR_S_BYTES    67112992ull   /* Sc bf16 32MB, in OFF_WZ region */
#define SCR_A_BYTES    132648976ull  /* Ab bf16 4MB,  in OFF_U region */
#define SCR_CAND_BYTES 136843296ull  /* u32[1024][512] = 2MB, in OFF_U region */

// ws float offsets
#define WS_INV_X    0
#define WS_INV_WX   1024
#define WS_INV_WZ   17408
#define WS_INV_U    33792
#define WS_FIDX     38912   /* int[1024] */
#define WS_CNT      39936   /* int[16384] */
#define WS_ZCNT     56320   /* int[1024] */
#define WS_SEGMIN   57344   /* uint[16384] */
#define WS_CTR      73728   /* int[8]: [0]=unact_cnt [1]=act_cnt [2]=min_act_idx */
#define WS_MBITS    73736   /* u64[256] */
#define WS_CCNT     74248   /* int[1024] */

typedef unsigned short ushort_t;
typedef __bf16 bf16x8 __attribute__((ext_vector_type(8)));
typedef float f32x4 __attribute__((ext_vector_type(4)));

__device__ __forceinline__ unsigned enc_f(float f) {
    unsigned u = __float_as_uint(f);
    return (u & 0x80000000u) ? ~u : (u | 0x80000000u);
}
__device__ __forceinline__ float dec_f(unsigned e) {
    unsigned u = (e & 0x80000000u) ? (e ^ 0x80000000u) : ~e;
    return __uint_as_float(u);
}
__device__ __forceinline__ unsigned long long pack_vi(float v, int y) {
    return ((unsigned long long)enc_f(v) << 32) |
           (unsigned long long)(0xFFFFFFFFu - (unsigned)y);
}
__device__ __forceinline__ ushort_t f2b(float f) {
    unsigned u = __float_as_uint(f);
    return (ushort_t)((u + 0x7FFFu + ((u >> 16) & 1u)) >> 16);
}
__device__ __forceinline__ float b2f(unsigned lo16) {
    return __uint_as_float(lo16 << 16);
}

#define GLOAD16(gp, lp) __builtin_amdgcn_global_load_lds( \
    (const __attribute__((address_space(1))) void*)(gp),  \
    (__attribute__((address_space(3))) void*)(lp), 16, 0, 0)

__global__ void init_kernel(int* cnt, unsigned* segmin, int* zcnt, int* ctr) {
    int i = blockIdx.x * 256 + threadIdx.x;
    if (i < Y_N) { cnt[i] = 0; segmin[i] = 0xFFFFFFFFu; }
    if (i < 1024) zcnt[i] = 0;
    if (i < 8) ctr[i] = (i == 2) ? 0x7FFFFFFF : 0;
}

__global__ void rownorm_kernel(const float* __restrict__ src, int rowlen,
                               float* __restrict__ inv_out) {
    int row = blockIdx.x;
    const float* p = src + (size_t)row * rowlen;
    float ss = 0.f;
    for (int e = threadIdx.x; e < rowlen; e += 256) { float v = p[e]; ss += v * v; }
    #pragma unroll
    for (int s = 32; s > 0; s >>= 1) ss += __shfl_xor(ss, s, 64);
    __shared__ float red[4];
    if ((threadIdx.x & 63) == 0) red[threadIdx.x >> 6] = ss;
    __syncthreads();
    if (threadIdx.x == 0) {
        float tot = red[0] + red[1] + red[2] + red[3];
        inv_out[row] = 1.0f / fmaxf(sqrtf(tot), 1e-12f);
    }
}

__global__ void unact_kernel(const float* __restrict__ y_age, int* ctr,
                             unsigned long long* __restrict__ mbits) {
    int i = blockIdx.x * 256 + threadIdx.x;
    int a = (y_age[i] < 1.0f) ? 1 : 0;
    unsigned long long m = __ballot(a);
    int mi = a ? 0x7FFFFFFF : i;   // min index over ACTIVATED neurons
    #pragma unroll
    for (int s = 32; s > 0; s >>= 1) mi = min(mi, __shfl_xor(mi, s, 64));
    if ((threadIdx.x & 63) == 0) {
        atomicAdd(ctr, (int)__popcll(m));
        mbits[i >> 6] = m;
        if (mi != 0x7FFFFFFF) atomicMin(&ctr[2], mi);
    }
}

// A [B_N][GK] bf16: cols 0..1023 = 0.5*x_hat ; cols 1024.. = 0.5*one_hot(z)
__global__ void pack_x_kernel(const float* __restrict__ x, const float* __restrict__ inv_x,
                              const int* __restrict__ zlab, ushort_t* __restrict__ A) {
    int i = blockIdx.x * 256 + threadIdx.x;
    int idx = i * 8;
    int bb = idx >> 11;
    int k = idx & (GK - 1);
    ushort_t o[8];
    if (k < X_N) {
        float invx = 0.5f * inv_x[bb];
        const float* xr = x + (size_t)bb * X_N + k;
        #pragma unroll
        for (int j = 0; j < 8; ++j) o[j] = f2b(invx * xr[j]);
    } else {
        int zb = zlab[bb];
        #pragma unroll
        for (int j = 0; j < 8; ++j) o[j] = ((k + j - X_N) == zb) ? (ushort_t)0x3F00 : (ushort_t)0;
    }
    *reinterpret_cast<uint4*>(A + idx) = *reinterpret_cast<uint4*>(o);
}

// B [Y_N][GK] bf16: cols 0..1023 = Wx_hat ; 1024..2023 = Wz_hat ; rest 0
__global__ void pack_w_kernel(const float* __restrict__ wxw, const float* __restrict__ inv_wx,
                              const float* __restrict__ wzw, const float* __restrict__ inv_wz,
                              ushort_t* __restrict__ Bm) {
    int i = blockIdx.x * 256 + threadIdx.x;
    size_t idx = (size_t)i * 8;
    int y = (int)(idx >> 11);
    int k = (int)(idx & (GK - 1));
    ushort_t o[8];
    if (k < X_N) {
        float s = inv_wx[y];
        const float* wr = wxw + (size_t)y * X_N + k;
        #pragma unroll
        for (int j = 0; j < 8; ++j) o[j] = f2b(s * wr[j]);
    } else if (k < X_N + Z_N) {
        float s = inv_wz[y];
        const float* wr = wzw + (size_t)y * Z_N + (k - X_N);
        #pragma unroll
        for (int j = 0; j < 8; ++j) o[j] = f2b(s * wr[j]);
    } else {
        #pragma unroll
        for (int j = 0; j < 8; ++j) o[j] = 0;
    }
    *reinterpret_cast<uint4*>(Bm + idx) = *reinterpret_cast<uint4*>(o);
}

// bf16 MFMA GEMM, 256x256 tile, BK=64, 8 waves (2Mx4N), fragment-major LDS.
// XCD-chunked bid swizzle: each XCD owns a contiguous set of nt panels.
__global__ __launch_bounds__(512, 2) void mm256_kernel(const ushort_t* __restrict__ A,
                                                       const ushort_t* __restrict__ Bm,
                                                       ushort_t* __restrict__ S) {
    // [buf][mat][slot = g*256 + row][8 bf16]; g in [0,8) covers BK=64
    __shared__ __align__(16) ushort_t lds[2][2][2048][8];
    const int t = threadIdx.x;
    const int wid = t >> 6, lane = t & 63;
    const int bid = blockIdx.x;
    const int lb = (bid & 7) * 32 + (bid >> 3);   // bijective: 256 % 8 == 0
    const int mt = lb & 3, nt = lb >> 2;
    const int b0 = mt * 256, y0 = nt * 256;
    const int wr = wid >> 2, wc = wid & 3;        // 2 x 4 waves
    const int r = lane & 15, gq = lane >> 4;

    f32x4 acc[8][4];
    #pragma unroll
    for (int i = 0; i < 8; ++i)
        #pragma unroll
        for (int j = 0; j < 4; ++j) acc[i][j] = (f32x4){0.f, 0.f, 0.f, 0.f};

    auto stage = [&](int buf, int k0) {
        #pragma unroll
        for (int rr = 0; rr < 4; ++rr) {
            int s = rr * 512 + t;           // lane-linear LDS slots
            int row = s & 255, g = s >> 8;
            GLOAD16(A  + (size_t)(b0 + row) * GK + k0 + g * 8, &lds[buf][0][s][0]);
            GLOAD16(Bm + (size_t)(y0 + row) * GK + k0 + g * 8, &lds[buf][1][s][0]);
        }
    };

    stage(0, 0);
    __syncthreads();
    int cur = 0;
    for (int ks = 0; ks < GK / 64; ++ks) {
        if (ks < GK / 64 - 1) stage(cur ^ 1, (ks + 1) * 64);
        #pragma unroll
        for (int kk = 0; kk < 2; ++kk) {
            const int g = kk * 4 + gq;
            bf16x8 aF[8], bF[4];
            #pragma unroll
            for (int mf = 0; mf < 8; ++mf)
                aF[mf] = *reinterpret_cast<const bf16x8*>(
                    &lds[cur][0][g * 256 + wr * 128 + mf * 16 + r][0]);
            #pragma unroll
            for (int nf = 0; nf < 4; ++nf)
                bF[nf] = *reinterpret_cast<const bf16x8*>(
                    &lds[cur][1][g * 256 + wc * 64 + nf * 16 + r][0]);
            __builtin_amdgcn_s_setprio(1);
            #pragma unroll
            for (int mf = 0; mf < 8; ++mf)
                #pragma unroll
                for (int nf = 0; nf < 4; ++nf)
                    acc[mf][nf] = __builtin_amdgcn_mfma_f32_16x16x32_bf16(
                        aF[mf], bF[nf], acc[mf][nf], 0, 0, 0);
            __builtin_amdgcn_s_setprio(0);
        }
        __syncthreads();   // drains vmcnt+lgkm; next buffer ready
        cur ^= 1;
    }

    // C layout: col = lane&15, row = (lane>>4)*4 + reg
    #pragma unroll
    for (int mf = 0; mf < 8; ++mf) {
        int bg = b0 + wr * 128 + mf * 16 + gq * 4;
        #pragma unroll
        for (int nf = 0; nf < 4; ++nf) {
            int yg = y0 + wc * 64 + nf * 16 + r;
            f32x4 c = acc[mf][nf];
            #pragma unroll
            for (int q = 0; q < 4; ++q)
                S[(size_t)(bg + q) * Y_N + yg] = f2b(c[q]);
        }
    }
}

// per-row: approx max + candidate collection (per-row slab, LDS atomics only)
__global__ __launch_bounds__(256) void scan_kernel(
    const ushort_t* __restrict__ scores, const unsigned long long* __restrict__ mbits,
    const int* __restrict__ ctr, unsigned* __restrict__ gcand, int* __restrict__ ccnt) {
    const int b = blockIdx.x, t = threadIdx.x;
    const int lane = t & 63, wid = t >> 6;
    const uint4* srow = reinterpret_cast<const uint4*>(scores + (size_t)b * Y_N);

    float vmax = -1e30f, mmax = -1e30f;
    for (int c = t; c < Y_N / 8; c += 256) {
        uint4 pk = srow[c];
        int yb = c * 8;
        unsigned m8 = (unsigned)((mbits[yb >> 6] >> (yb & 63)) & 0xFFull);
        unsigned w[4] = {pk.x, pk.y, pk.z, pk.w};
        #pragma unroll
        for (int j = 0; j < 4; ++j) {
            float v0 = b2f(w[j] & 0xFFFFu);
            float v1 = b2f(w[j] >> 16);
            vmax = fmaxf(vmax, fmaxf(v0, v1));
            mmax = fmaxf(mmax, v0 * (float)((m8 >> (2 * j)) & 1u));
            mmax = fmaxf(mmax, v1 * (float)((m8 >> (2 * j + 1)) & 1u));
        }
    }
    #pragma unroll
    for (int s = 32; s > 0; s >>= 1) {
        vmax = fmaxf(vmax, __shfl_xor(vmax, s, 64));
        mmax = fmaxf(mmax, __shfl_xor(mmax, s, 64));
    }
    __shared__ float rv[4], rm[4];
    __shared__ int nA_s, nB_s;
    __shared__ int cA[256], cB[256];
    if (lane == 0) { rv[wid] = vmax; rm[wid] = mmax; }
    if (t == 0) { nA_s = 0; nB_s = 0; }
    __syncthreads();
    float tA = fmaxf(fmaxf(rv[0], rv[1]), fmaxf(rv[2], rv[3])) - MARGIN;
    float tB = fmaxf(fmaxf(rm[0], rm[1]), fmaxf(rm[2], rm[3])) - MARGIN;
    bool anyu = ctr[0] > 0;

    for (int c = t; c < Y_N / 8; c += 256) {
        uint4 pk = srow[c];
        int yb = c * 8;
        unsigned m8 = (unsigned)((mbits[yb >> 6] >> (yb & 63)) & 0xFFull);
        unsigned w[4] = {pk.x, pk.y, pk.z, pk.w};
        #pragma unroll
        for (int j = 0; j < 8; ++j) {
            float v = b2f((j & 1) ? (w[j >> 1] >> 16) : (w[j >> 1] & 0xFFFFu));
            if (v >= tA) { int p = atomicAdd(&nA_s, 1); if (p < 256) cA[p] = yb + j; }
            if (anyu && ((m8 >> j) & 1u) && v >= tB) {
                int p = atomicAdd(&nB_s, 1); if (p < 256) cB[p] = yb + j;
            }
        }
    }
    __syncthreads();
    int nA = min(nA_s, 256), nB = min(nB_s, 256);
    unsigned* slab = gcand + (size_t)b * 512;
    for (int i = t; i < nA; i += 256) slab[i] = (unsigned)cA[i];
    for (int i = t; i < nB; i += 256) slab[256 + i] = (unsigned)cB[i];
    if (t == 0) ccnt[b] = nA | (nB << 16);
}

// per-row: exact fp32 rescore of candidates + finalize
__global__ __launch_bounds__(256) void rescore_kernel(
    const unsigned* __restrict__ gcand, const int* __restrict__ ccnt,
    const float* __restrict__ x, const float* __restrict__ inv_x,
    const float* __restrict__ wxw, const float* __restrict__ inv_wx,
    const float* __restrict__ wzw, const float* __restrict__ inv_wz,
    const int* __restrict__ zlab, const float* __restrict__ y_thr,
    const float* __restrict__ y_age, const int* __restrict__ ctr,
    int* final_idx, int* cnt, unsigned* segmin, int* zcnt,
    float* __restrict__ out_maxresp) {
    const int b = blockIdx.x, t = threadIdx.x;
    const int lane = t & 63, wid = t >> 6;
    int pc = ccnt[b];
    int nA = pc & 0xFFFF, nB = pc >> 16;
    int zb = zlab[b];
    float invx = inv_x[b];
    const unsigned* slab = gcand + (size_t)b * 512;

    const float4* xr = reinterpret_cast<const float4*>(x + (size_t)b * X_N);
    float4 xv[4];
    #pragma unroll
    for (int j = 0; j < 4; ++j) xv[j] = xr[j * 64 + lane];

    unsigned long long bA = 0ull, bB = 0ull;
    int tot = nA + nB;
    for (int c = wid; c < tot; c += 4) {
        bool isB = c >= nA;
        int y = (int)slab[isB ? (256 + c - nA) : c];
        const float4* wp = reinterpret_cast<const float4*>(wxw + (size_t)y * X_N);
        float dot = 0.f;
        #pragma unroll
        for (int j = 0; j < 4; ++j) {
            float4 wv = wp[j * 64 + lane];
            dot += xv[j].x * wv.x + xv[j].y * wv.y + xv[j].z * wv.z + xv[j].w * wv.w;
        }
        #pragma unroll
        for (int s = 32; s > 0; s >>= 1) dot += __shfl_xor(dot, s, 64);
        float val = 0.5f * invx * inv_wx[y] * dot + 0.5f * inv_wz[y] * wzw[(size_t)y * Z_N + zb];
        unsigned long long p = pack_vi(val, y);
        if (isB) bB = (p > bB) ? p : bB;
        else     bA = (p > bA) ? p : bA;
    }
    __shared__ unsigned long long rA[4], rB[4];
    if (lane == 0) { rA[wid] = bA; rB[wid] = bB; }
    __syncthreads();
    if (t == 0) {
        unsigned long long pm = rA[0], pf = rB[0];
        #pragma unroll
        for (int j = 1; j < 4; ++j) {
            pm = (rA[j] > pm) ? rA[j] : pm;
            pf = (rB[j] > pf) ? rB[j] : pf;
        }
        unsigned enc = (unsigned)(pm >> 32);
        int idx = (int)(0xFFFFFFFFu - (unsigned)(pm & 0xFFFFFFFFull));
        float mresp = dec_f(enc);
        out_maxresp[b] = mresp;
        bool judge = (mresp > y_thr[idx]) || (y_age[idx] < 1.0f);
        bool anyu = ctr[0] > 0;
        int fi = (nB > 0) ? (int)(0xFFFFFFFFu - (unsigned)(pf & 0xFFFFFFFFull))
                          : ctr[2];   // all-unact-negative: ref argmax picks first activated (0)
        int fin = (judge || !anyu) ? idx : fi;
        final_idx[b] = fin;
        atomicAdd(&cnt[fin], 1);
        atomicMin(&segmin[fin], enc);
        atomicAdd(&zcnt[zb], 1);
    }
}

__global__ void wx_out_kernel(const float* __restrict__ wxw, const float* __restrict__ inv_wx,
                              const float* __restrict__ x, const float* __restrict__ inv_x,
                              const int* __restrict__ final_idx, const int* __restrict__ cnt,
                              const float* __restrict__ y_age, float* __restrict__ outw) {
    int j = blockIdx.x;
    int t = threadIdx.x;
    __shared__ int s_b[1024];
    __shared__ int s_n;
    if (t == 0) s_n = 0;
    __syncthreads();
    int c = cnt[j];
    if (c > 0) {
        for (int b = t; b < B_N; b += 256)
            if (final_idx[b] == j) { int p = atomicAdd(&s_n, 1); s_b[p] = b; }
    }
    __syncthreads();
    float inv = inv_wx[j];
    float lr = 1.0f / (y_age[j] + 1.0f);
    float fc = (float)c;
    float dv = (c > 0) ? fc : 1.0f;
    int n = s_n;
    float4 w = *reinterpret_cast<const float4*>(wxw + (size_t)j * X_N + t * 4);
    float4 wn = make_float4(w.x*inv, w.y*inv, w.z*inv, w.w*inv);
    if (c > 0) {
        float4 s = make_float4(0.f, 0.f, 0.f, 0.f);
        for (int m = 0; m < n; ++m) {
            int b = s_b[m];
            float ix = inv_x[b];
            float4 xv = *reinterpret_cast<const float4*>(x + (size_t)b * X_N + t * 4);
            s.x += xv.x * ix; s.y += xv.y * ix; s.z += xv.z * ix; s.w += xv.w * ix;
        }
        float f = lr / dv;
        wn.x += f * (s.x - fc * wn.x);
        wn.y += f * (s.y - fc * wn.y);
        wn.z += f * (s.z - fc * wn.z);
        wn.w += f * (s.w - fc * wn.w);
    }
    *reinterpret_cast<float4*>(outw + (size_t)j * X_N + t * 4) = wn;
}

__global__ void wz_out_kernel(const float* __restrict__ wzw, const float* __restrict__ inv_wz,
                              const int* __restrict__ zlab, const int* __restrict__ final_idx,
                              const int* __restrict__ cnt, const float* __restrict__ y_age,
                              float* __restrict__ outw) {
    int j = blockIdx.x;
    int t = threadIdx.x;
    __shared__ int s_c[1024];
    __shared__ int s_n;
    if (t == 0) s_n = 0;
    __syncthreads();
    int c = cnt[j];
    if (c > 0) {
        for (int b = t; b < B_N; b += 256)
            if (final_idx[b] == j) { int p = atomicAdd(&s_n, 1); s_c[p] = zlab[b]; }
    }
    __syncthreads();
    if (t >= 250) return;
    float inv = inv_wz[j];
    float lr = 1.0f / (y_age[j] + 1.0f);
    float fc = (float)c;
    float dv = (c > 0) ? fc : 1.0f;
    int n = s_n;
    float4 w = *reinterpret_cast<const float4*>(wzw + (size_t)j * Z_N + t * 4);
    float4 wn = make_float4(w.x*inv, w.y*inv, w.z*inv, w.w*inv);
    if (c > 0) {
        float4 s = make_float4(0.f, 0.f, 0.f, 0.f);
        for (int m = 0; m < n; ++m) {
            int d = s_c[m] - t * 4;
            if (d == 0) s.x += 1.f;
            else if (d == 1) s.y += 1.f;
            else if (d == 2) s.z += 1.f;
            else if (d == 3) s.w += 1.f;
        }
        float f = lr / dv;
        wn.x += f * (s.x - fc * wn.x);
        wn.y += f * (s.y - fc * wn.y);
        wn.z += f * (s.z - fc * wn.z);
        wn.w += f * (s.w - fc * wn.w);
    }
    *reinterpret_cast<float4*>(outw + (size_t)j * Z_N + t * 4) = wn;
}

__global__ void u_out_kernel(const float* __restrict__ uw, const float* __restrict__ inv_u,
                             const int* __restrict__ zlab, const int* __restrict__ final_idx,
                             const int* __restrict__ zcnt, const float* __restrict__ z_age,
                             float* __restrict__ outw) {
    int cz = blockIdx.x;
    int t = threadIdx.x;
    __shared__ int s_w[1024];
    __shared__ int s_n;
    if (t == 0) s_n = 0;
    __syncthreads();
    int c = zcnt[cz];
    if (c > 0) {
        for (int b = t; b < B_N; b += 256)
            if (zlab[b] == cz) { int p = atomicAdd(&s_n, 1); s_w[p] = final_idx[b]; }
    }
    __syncthreads();
    float inv = inv_u[cz];
    float zlr = 1.0f / (z_age[cz] + 1.0f);
    float fc = (float)c;
    float dv = (c > 0) ? fc : 1.0f;
    float f = zlr / dv;
    int n = s_n;
    const float* rowp = uw + (size_t)cz * Y_N;
    float* outp = outw + (size_t)cz * Y_N;
    for (int pass = 0; pass < 16; ++pass) {
        int e4 = pass * 256 + t;
        float4 u = *reinterpret_cast<const float4*>(rowp + e4 * 4);
        float4 un = make_float4(u.x*inv, u.y*inv, u.z*inv, u.w*inv);
        if (c > 0) {
            float4 s = make_float4(0.f, 0.f, 0.f, 0.f);
            for (int m = 0; m < n; ++m) {
                int d = s_w[m] - e4 * 4;
                if (d == 0) s.x += 1.f;
                else if (d == 1) s.y += 1.f;
                else if (d == 2) s.z += 1.f;
                else if (d == 3) s.w += 1.f;
            }
            un.x += f * (s.x - fc * un.x);
            un.y += f * (s.y - fc * un.y);
            un.z += f * (s.z - fc * un.z);
            un.w += f * (s.w - fc * un.w);
        }
        *reinterpret_cast<float4*>(outp + e4 * 4) = un;
    }
}

__global__ void thr_age_kernel(const int* __restrict__ cnt, const unsigned* __restrict__ segmin,
                               const float* __restrict__ y_age, const float* __restrict__ y_thr,
                               float* __restrict__ out_thr, float* __restrict__ out_age,
                               int* ctr) {
    int j = blockIdx.x * 256 + threadIdx.x;
    int c = cnt[j];
    float age = y_age[j];
    float thr = y_thr[j];
    float tn = thr;
    if (c > 0) {
        float lr = 1.0f / (age + 1.0f);
        float smin = dec_f(segmin[j]);
        float ycur = fminf(smin, 3.0f);
        if (ycur > 2.0f) ycur = 0.0f;
        tn = lr * ycur + (1.0f - lr) * thr;
    }
    out_thr[j] = tn;
    float an = age + (float)c;
    out_age[j] = an;
    unsigned long long m = __ballot(an >= 1.0f ? 1 : 0);
    if ((threadIdx.x & 63) == 0) atomicAdd(ctr + 1, (int)__popcll(m));
}

__global__ void zage_act_kernel(const int* __restrict__ zcnt, const float* __restrict__ z_age,
                                const int* __restrict__ ctr, float* __restrict__ out_zage,
                                float* __restrict__ out_act) {
    int i = blockIdx.x * 256 + threadIdx.x;
    if (i < Z_N) out_zage[i] = z_age[i] + (float)zcnt[i];
    if (i == 0) out_act[0] = (float)ctr[1];
}

extern "C" void kernel_launch(void* const* d_in, const int* in_sizes, int n_in,
                              void* d_out, int out_size, void* d_ws, size_t ws_size,
                              hipStream_t stream) {
    const float* x     = (const float*)d_in[0];
    const int*   z     = (const int*)d_in[1];
    const float* wxw   = (const float*)d_in[2];
    const float* wzw   = (const float*)d_in[3];
    const float* uw    = (const float*)d_in[4];
    const float* y_age = (const float*)d_in[5];
    const float* z_age = (const float*)d_in[6];
    const float* y_thr = (const float*)d_in[7];
    float* out = (float*)d_out;
    float* ws  = (float*)d_ws;
    char*  ob  = (char*)d_out;

    float* inv_x  = ws + WS_INV_X;
    float* inv_wx = ws + WS_INV_WX;
    float* inv_wz = ws + WS_INV_WZ;
    float* inv_u  = ws + WS_INV_U;
    int* fidx = (int*)(ws + WS_FIDX);
    int* cnt  = (int*)(ws + WS_CNT);
    int* zcnt = (int*)(ws + WS_ZCNT);
    unsigned* segmin = (unsigned*)(ws + WS_SEGMIN);
    int* ctr = (int*)(ws + WS_CTR);
    unsigned long long* mbits = (unsigned long long*)(ws + WS_MBITS);
    int* ccnt = (int*)(ws + WS_CCNT);

    ushort_t* Bb = (ushort_t*)(ob + SCR_B_BYTES);
    ushort_t* Sc = (ushort_t*)(ob + SCR_S_BYTES);
    ushort_t* Ab = (ushort_t*)(ob + SCR_A_BYTES);
    unsigned* gcand = (unsigned*)(ob + SCR_CAND_BYTES);

    init_kernel<<<64, 256, 0, stream>>>(cnt, segmin, zcnt, ctr);
    rownorm_kernel<<<B_N, 256, 0, stream>>>(x, X_N, inv_x);
    rownorm_kernel<<<Y_N, 256, 0, stream>>>(wxw, X_N, inv_wx);
    rownorm_kernel<<<Y_N, 256, 0, stream>>>(wzw, Z_N, inv_wz);
    rownorm_kernel<<<Z_N, 256, 0, stream>>>(uw, Y_N, inv_u);
    unact_kernel<<<Y_N / 256, 256, 0, stream>>>(y_age, ctr, mbits);
    pack_x_kernel<<<(B_N * GK / 8) / 256, 256, 0, stream>>>(x, inv_x, z, Ab);
    pack_w_kernel<<<(Y_N * GK / 8) / 256, 256, 0, stream>>>(wxw, inv_wx, wzw, inv_wz, Bb);
    mm256_kernel<<<(B_N / 256) * (Y_N / 256), 512, 0, stream>>>(Ab, Bb, Sc);
    scan_kernel<<<B_N, 256, 0, stream>>>(Sc, mbits, ctr, gcand, ccnt);
    rescore_kernel<<<B_N, 256, 0, stream>>>(gcand, ccnt, x, inv_x, wxw, inv_wx, wzw, inv_wz,
                                            z, y_thr, y_age, ctr, fidx, cnt, segmin, zcnt,
                                            out + OFF_MAXRESP);
    wx_out_kernel<<<Y_N, 256, 0, stream>>>(wxw, inv_wx, x, inv_x, fidx, cnt, y_age, out + OFF_WX);
    wz_out_kernel<<<Y_N, 256, 0, stream>>>(wzw, inv_wz, z, fidx, cnt, y_age, out + OFF_WZ);
    u_out_kernel<<<Z_N, 256, 0, stream>>>(uw, inv_u, z, fidx, zcnt, z_age, out + OFF_U);
    thr_age_kernel<<<Y_N / 256, 256, 0, stream>>>(cnt, segmin, y_age, y_thr,
                                                  out + OFF_THR, out + OFF_AGE, ctr);
    zage_act_kernel<<<4, 256, 0, stream>>>(zcnt, z_age, ctr, out + OFF_ZAGE, out + OFF_ACT);
}

// Round 5
// 377.326 us; speedup vs baseline: 1.4832x; 1.4832x over previous
//
#include <hip/hip_runtime.h>

#define B_N 1024
#define X_N 1024
#define Y_N 16384
#define Z_N 1000
#define GK  2048
#define MARGIN 0.009f

// output float offsets
#define OFF_ACT      0
#define OFF_MAXRESP  1
#define OFF_WX       1025
#define OFF_WZ       16778241
#define OFF_U        33162241
#define OFF_THR      49546241
#define OFF_AGE      49562625
#define OFF_ZAGE     49579009

// scratch placed inside not-yet-written d_out regions (16B aligned byte offsets)
#define SCR_B_BYTES    4112ull       /* Bb bf16 64MB, in OFF_WX region */
#define SCR_S_BYTES    67112992ull   /* Sc bf16 32MB, in OFF_WZ region */
#define SCR_A_BYTES    132648976ull  /* Ab bf16 4MB,  in OFF_U region */
#define SCR_CAND_BYTES 136843296ull  /* u32[1024][512] = 2MB, in OFF_U region */

// ws float offsets
#define WS_INV_X    0
#define WS_INV_WX   1024
#define WS_INV_WZ   17408
#define WS_INV_U    33792
#define WS_FIDX     38912   /* int[1024] */
#define WS_CNT      39936   /* int[16384] */
#define WS_ZCNT     56320   /* int[1024] */
#define WS_SEGMIN   57344   /* uint[16384] */
#define WS_CTR      73728   /* int[8]: [0]=unact_cnt [1]=act_cnt [2]=min_act_idx */
#define WS_MBITS    73736   /* u64[256] */
#define WS_CCNT     74248   /* int[1024] */

typedef unsigned short ushort_t;
typedef __bf16 bf16x8 __attribute__((ext_vector_type(8)));
typedef float f32x4 __attribute__((ext_vector_type(4)));

__device__ __forceinline__ unsigned enc_f(float f) {
    unsigned u = __float_as_uint(f);
    return (u & 0x80000000u) ? ~u : (u | 0x80000000u);
}
__device__ __forceinline__ float dec_f(unsigned e) {
    unsigned u = (e & 0x80000000u) ? (e ^ 0x80000000u) : ~e;
    return __uint_as_float(u);
}
__device__ __forceinline__ unsigned long long pack_vi(float v, int y) {
    return ((unsigned long long)enc_f(v) << 32) |
           (unsigned long long)(0xFFFFFFFFu - (unsigned)y);
}
__device__ __forceinline__ ushort_t f2b(float f) {
    unsigned u = __float_as_uint(f);
    return (ushort_t)((u + 0x7FFFu + ((u >> 16) & 1u)) >> 16);
}
__device__ __forceinline__ float b2f(unsigned lo16) {
    return __uint_as_float(lo16 << 16);
}

#define GLOAD16(gp, lp) __builtin_amdgcn_global_load_lds( \
    (const __attribute__((address_space(1))) void*)(gp),  \
    (__attribute__((address_space(3))) void*)(lp), 16, 0, 0)

__global__ void init_kernel(int* cnt, unsigned* segmin, int* zcnt, int* ctr) {
    int i = blockIdx.x * 256 + threadIdx.x;
    if (i < Y_N) { cnt[i] = 0; segmin[i] = 0xFFFFFFFFu; }
    if (i < 1024) zcnt[i] = 0;
    if (i < 8) ctr[i] = (i == 2) ? 0x7FFFFFFF : 0;
}

__global__ void rownorm_kernel(const float* __restrict__ src, int rowlen,
                               float* __restrict__ inv_out) {
    int row = blockIdx.x;
    const float* p = src + (size_t)row * rowlen;
    float ss = 0.f;
    for (int e = threadIdx.x; e < rowlen; e += 256) { float v = p[e]; ss += v * v; }
    #pragma unroll
    for (int s = 32; s > 0; s >>= 1) ss += __shfl_xor(ss, s, 64);
    __shared__ float red[4];
    if ((threadIdx.x & 63) == 0) red[threadIdx.x >> 6] = ss;
    __syncthreads();
    if (threadIdx.x == 0) {
        float tot = red[0] + red[1] + red[2] + red[3];
        inv_out[row] = 1.0f / fmaxf(sqrtf(tot), 1e-12f);
    }
}

__global__ void unact_kernel(const float* __restrict__ y_age, int* ctr,
                             unsigned long long* __restrict__ mbits) {
    int i = blockIdx.x * 256 + threadIdx.x;
    int a = (y_age[i] < 1.0f) ? 1 : 0;
    unsigned long long m = __ballot(a);
    int mi = a ? 0x7FFFFFFF : i;   // min index over ACTIVATED neurons
    #pragma unroll
    for (int s = 32; s > 0; s >>= 1) mi = min(mi, __shfl_xor(mi, s, 64));
    if ((threadIdx.x & 63) == 0) {
        atomicAdd(ctr, (int)__popcll(m));
        mbits[i >> 6] = m;
        if (mi != 0x7FFFFFFF) atomicMin(&ctr[2], mi);
    }
}

// A [B_N][GK] bf16: cols 0..1023 = 0.5*x_hat ; cols 1024.. = 0.5*one_hot(z)
__global__ void pack_x_kernel(const float* __restrict__ x, const float* __restrict__ inv_x,
                              const int* __restrict__ zlab, ushort_t* __restrict__ A) {
    int i = blockIdx.x * 256 + threadIdx.x;
    int idx = i * 8;
    int bb = idx >> 11;
    int k = idx & (GK - 1);
    ushort_t o[8];
    if (k < X_N) {
        float invx = 0.5f * inv_x[bb];
        const float* xr = x + (size_t)bb * X_N + k;
        #pragma unroll
        for (int j = 0; j < 8; ++j) o[j] = f2b(invx * xr[j]);
    } else {
        int zb = zlab[bb];
        #pragma unroll
        for (int j = 0; j < 8; ++j) o[j] = ((k + j - X_N) == zb) ? (ushort_t)0x3F00 : (ushort_t)0;
    }
    *reinterpret_cast<uint4*>(A + idx) = *reinterpret_cast<uint4*>(o);
}

// fused: row-norms of wxw/wzw + pack B row [Y_N][GK] bf16 (one block per y)
__global__ __launch_bounds__(256) void pack_w_kernel(
    const float* __restrict__ wxw, const float* __restrict__ wzw,
    ushort_t* __restrict__ Bm, float* __restrict__ inv_wx, float* __restrict__ inv_wz) {
    const int y = blockIdx.x, t = threadIdx.x;
    const int lane = t & 63, wid = t >> 6;
    float4 a = reinterpret_cast<const float4*>(wxw + (size_t)y * X_N)[t];
    float4 zv = make_float4(0.f, 0.f, 0.f, 0.f);
    if (t < 250) zv = reinterpret_cast<const float4*>(wzw + (size_t)y * Z_N)[t];
    float s1 = a.x*a.x + a.y*a.y + a.z*a.z + a.w*a.w;
    float s2 = zv.x*zv.x + zv.y*zv.y + zv.z*zv.z + zv.w*zv.w;
    #pragma unroll
    for (int s = 32; s > 0; s >>= 1) {
        s1 += __shfl_xor(s1, s, 64);
        s2 += __shfl_xor(s2, s, 64);
    }
    __shared__ float r1[4], r2[4];
    if (lane == 0) { r1[wid] = s1; r2[wid] = s2; }
    __syncthreads();
    float inv1 = 1.0f / fmaxf(sqrtf(r1[0] + r1[1] + r1[2] + r1[3]), 1e-12f);
    float inv2 = 1.0f / fmaxf(sqrtf(r2[0] + r2[1] + r2[2] + r2[3]), 1e-12f);
    ushort_t o1[4] = { f2b(a.x*inv1), f2b(a.y*inv1), f2b(a.z*inv1), f2b(a.w*inv1) };
    *reinterpret_cast<uint2*>(Bm + (size_t)y * GK + t * 4) = *reinterpret_cast<uint2*>(o1);
    ushort_t o2[4] = { 0, 0, 0, 0 };
    if (t < 250) { o2[0]=f2b(zv.x*inv2); o2[1]=f2b(zv.y*inv2); o2[2]=f2b(zv.z*inv2); o2[3]=f2b(zv.w*inv2); }
    *reinterpret_cast<uint2*>(Bm + (size_t)y * GK + X_N + t * 4) = *reinterpret_cast<uint2*>(o2);
    if (t == 0) { inv_wx[y] = inv1; inv_wz[y] = inv2; }
}

// bf16 MFMA GEMM, 256x256 tile, BK=64, 8 waves (2Mx4N), fragment-major LDS.
__global__ __launch_bounds__(512, 2) void mm256_kernel(const ushort_t* __restrict__ A,
                                                       const ushort_t* __restrict__ Bm,
                                                       ushort_t* __restrict__ S) {
    __shared__ __align__(16) ushort_t lds[2][2][2048][8];
    const int t = threadIdx.x;
    const int wid = t >> 6, lane = t & 63;
    const int bid = blockIdx.x;
    const int lb = (bid & 7) * 32 + (bid >> 3);   // bijective: 256 % 8 == 0
    const int mt = lb & 3, nt = lb >> 2;
    const int b0 = mt * 256, y0 = nt * 256;
    const int wr = wid >> 2, wc = wid & 3;        // 2 x 4 waves
    const int r = lane & 15, gq = lane >> 4;

    f32x4 acc[8][4];
    #pragma unroll
    for (int i = 0; i < 8; ++i)
        #pragma unroll
        for (int j = 0; j < 4; ++j) acc[i][j] = (f32x4){0.f, 0.f, 0.f, 0.f};

    auto stage = [&](int buf, int k0) {
        #pragma unroll
        for (int rr = 0; rr < 4; ++rr) {
            int s = rr * 512 + t;
            int row = s & 255, g = s >> 8;
            GLOAD16(A  + (size_t)(b0 + row) * GK + k0 + g * 8, &lds[buf][0][s][0]);
            GLOAD16(Bm + (size_t)(y0 + row) * GK + k0 + g * 8, &lds[buf][1][s][0]);
        }
    };

    stage(0, 0);
    __syncthreads();
    int cur = 0;
    for (int ks = 0; ks < GK / 64; ++ks) {
        if (ks < GK / 64 - 1) stage(cur ^ 1, (ks + 1) * 64);
        #pragma unroll
        for (int kk = 0; kk < 2; ++kk) {
            const int g = kk * 4 + gq;
            bf16x8 aF[8], bF[4];
            #pragma unroll
            for (int mf = 0; mf < 8; ++mf)
                aF[mf] = *reinterpret_cast<const bf16x8*>(
                    &lds[cur][0][g * 256 + wr * 128 + mf * 16 + r][0]);
            #pragma unroll
            for (int nf = 0; nf < 4; ++nf)
                bF[nf] = *reinterpret_cast<const bf16x8*>(
                    &lds[cur][1][g * 256 + wc * 64 + nf * 16 + r][0]);
            __builtin_amdgcn_s_setprio(1);
            #pragma unroll
            for (int mf = 0; mf < 8; ++mf)
                #pragma unroll
                for (int nf = 0; nf < 4; ++nf)
                    acc[mf][nf] = __builtin_amdgcn_mfma_f32_16x16x32_bf16(
                        aF[mf], bF[nf], acc[mf][nf], 0, 0, 0);
            __builtin_amdgcn_s_setprio(0);
        }
        __syncthreads();
        cur ^= 1;
    }

    #pragma unroll
    for (int mf = 0; mf < 8; ++mf) {
        int bg = b0 + wr * 128 + mf * 16 + gq * 4;
        #pragma unroll
        for (int nf = 0; nf < 4; ++nf) {
            int yg = y0 + wc * 64 + nf * 16 + r;
            f32x4 c = acc[mf][nf];
            #pragma unroll
            for (int q = 0; q < 4; ++q)
                S[(size_t)(bg + q) * Y_N + yg] = f2b(c[q]);
        }
    }
}

// per-row: approx max + candidate collection (per-row slab, LDS atomics only)
__global__ __launch_bounds__(256) void scan_kernel(
    const ushort_t* __restrict__ scores, const unsigned long long* __restrict__ mbits,
    const int* __restrict__ ctr, unsigned* __restrict__ gcand, int* __restrict__ ccnt) {
    const int b = blockIdx.x, t = threadIdx.x;
    const int lane = t & 63, wid = t >> 6;
    const uint4* srow = reinterpret_cast<const uint4*>(scores + (size_t)b * Y_N);

    float vmax = -1e30f, mmax = -1e30f;
    for (int c = t; c < Y_N / 8; c += 256) {
        uint4 pk = srow[c];
        int yb = c * 8;
        unsigned m8 = (unsigned)((mbits[yb >> 6] >> (yb & 63)) & 0xFFull);
        unsigned w[4] = {pk.x, pk.y, pk.z, pk.w};
        #pragma unroll
        for (int j = 0; j < 4; ++j) {
            float v0 = b2f(w[j] & 0xFFFFu);
            float v1 = b2f(w[j] >> 16);
            vmax = fmaxf(vmax, fmaxf(v0, v1));
            mmax = fmaxf(mmax, v0 * (float)((m8 >> (2 * j)) & 1u));
            mmax = fmaxf(mmax, v1 * (float)((m8 >> (2 * j + 1)) & 1u));
        }
    }
    #pragma unroll
    for (int s = 32; s > 0; s >>= 1) {
        vmax = fmaxf(vmax, __shfl_xor(vmax, s, 64));
        mmax = fmaxf(mmax, __shfl_xor(mmax, s, 64));
    }
    __shared__ float rv[4], rm[4];
    __shared__ int nA_s, nB_s;
    __shared__ int cA[256], cB[256];
    if (lane == 0) { rv[wid] = vmax; rm[wid] = mmax; }
    if (t == 0) { nA_s = 0; nB_s = 0; }
    __syncthreads();
    float tA = fmaxf(fmaxf(rv[0], rv[1]), fmaxf(rv[2], rv[3])) - MARGIN;
    float tB = fmaxf(fmaxf(rm[0], rm[1]), fmaxf(rm[2], rm[3])) - MARGIN;
    bool anyu = ctr[0] > 0;

    for (int c = t; c < Y_N / 8; c += 256) {
        uint4 pk = srow[c];
        int yb = c * 8;
        unsigned m8 = (unsigned)((mbits[yb >> 6] >> (yb & 63)) & 0xFFull);
        unsigned w[4] = {pk.x, pk.y, pk.z, pk.w};
        #pragma unroll
        for (int j = 0; j < 8; ++j) {
            float v = b2f((j & 1) ? (w[j >> 1] >> 16) : (w[j >> 1] & 0xFFFFu));
            if (v >= tA) { int p = atomicAdd(&nA_s, 1); if (p < 256) cA[p] = yb + j; }
            if (anyu && ((m8 >> j) & 1u) && v >= tB) {
                int p = atomicAdd(&nB_s, 1); if (p < 256) cB[p] = yb + j;
            }
        }
    }
    __syncthreads();
    int nA = min(nA_s, 256), nB = min(nB_s, 256);
    unsigned* slab = gcand + (size_t)b * 512;
    for (int i = t; i < nA; i += 256) slab[i] = (unsigned)cA[i];
    for (int i = t; i < nB; i += 256) slab[256 + i] = (unsigned)cB[i];
    if (t == 0) ccnt[b] = nA | (nB << 16);
}

// per-row: exact fp32 rescore (A list, judge, conditional B list) + finalize
__global__ __launch_bounds__(256) void rescore_kernel(
    const unsigned* __restrict__ gcand, const int* __restrict__ ccnt,
    const float* __restrict__ x, const float* __restrict__ inv_x,
    const float* __restrict__ wxw, const float* __restrict__ inv_wx,
    const float* __restrict__ wzw, const float* __restrict__ inv_wz,
    const int* __restrict__ zlab, const float* __restrict__ y_thr,
    const float* __restrict__ y_age, const int* __restrict__ ctr,
    int* final_idx, int* cnt, unsigned* segmin, int* zcnt,
    float* __restrict__ out_maxresp) {
    const int b = blockIdx.x, t = threadIdx.x;
    const int lane = t & 63, wid = t >> 6;
    int pc = ccnt[b];
    int nA = pc & 0xFFFF, nB = pc >> 16;
    int zb = zlab[b];
    float invx = inv_x[b];
    const unsigned* slab = gcand + (size_t)b * 512;

    const float4* xr = reinterpret_cast<const float4*>(x + (size_t)b * X_N);
    float4 xv[4];
    #pragma unroll
    for (int j = 0; j < 4; ++j) xv[j] = xr[j * 64 + lane];

    __shared__ unsigned long long red[4];
    __shared__ unsigned long long sPM;
    __shared__ int sTakeA;

    // ---- list A (2 candidates per wave-iteration for MLP) ----
    unsigned long long bA = 0ull;
    for (int c = wid; c < nA; c += 8) {
        int y1 = (int)slab[c];
        int c2 = c + 4;
        bool h2 = c2 < nA;
        int y2 = (int)slab[h2 ? c2 : c];
        const float4* w1 = reinterpret_cast<const float4*>(wxw + (size_t)y1 * X_N);
        const float4* w2 = reinterpret_cast<const float4*>(wxw + (size_t)y2 * X_N);
        float d1 = 0.f, d2 = 0.f;
        #pragma unroll
        for (int j = 0; j < 4; ++j) {
            float4 a1 = w1[j * 64 + lane];
            float4 a2 = w2[j * 64 + lane];
            d1 += xv[j].x*a1.x + xv[j].y*a1.y + xv[j].z*a1.z + xv[j].w*a1.w;
            d2 += xv[j].x*a2.x + xv[j].y*a2.y + xv[j].z*a2.z + xv[j].w*a2.w;
        }
        #pragma unroll
        for (int s = 32; s > 0; s >>= 1) {
            d1 += __shfl_xor(d1, s, 64);
            d2 += __shfl_xor(d2, s, 64);
        }
        float v1 = 0.5f*invx*inv_wx[y1]*d1 + 0.5f*inv_wz[y1]*wzw[(size_t)y1*Z_N + zb];
        unsigned long long p1 = pack_vi(v1, y1);
        bA = (p1 > bA) ? p1 : bA;
        if (h2) {
            float v2 = 0.5f*invx*inv_wx[y2]*d2 + 0.5f*inv_wz[y2]*wzw[(size_t)y2*Z_N + zb];
            unsigned long long p2 = pack_vi(v2, y2);
            bA = (p2 > bA) ? p2 : bA;
        }
    }
    if (lane == 0) red[wid] = bA;
    __syncthreads();
    if (t == 0) {
        unsigned long long pm = red[0];
        #pragma unroll
        for (int j = 1; j < 4; ++j) pm = (red[j] > pm) ? red[j] : pm;
        sPM = pm;
        unsigned enc = (unsigned)(pm >> 32);
        int idx = (int)(0xFFFFFFFFu - (unsigned)(pm & 0xFFFFFFFFull));
        float mresp = dec_f(enc);
        out_maxresp[b] = mresp;
        bool judge = (mresp > y_thr[idx]) || (y_age[idx] < 1.0f);
        bool anyu = ctr[0] > 0;
        sTakeA = (judge || !anyu) ? 1 : 0;
    }
    __syncthreads();

    // ---- list B only when fallback needed ----
    if (!sTakeA) {
        unsigned long long bB = 0ull;
        for (int c = wid; c < nB; c += 8) {
            int y1 = (int)slab[256 + c];
            int c2 = c + 4;
            bool h2 = c2 < nB;
            int y2 = (int)slab[256 + (h2 ? c2 : c)];
            const float4* w1 = reinterpret_cast<const float4*>(wxw + (size_t)y1 * X_N);
            const float4* w2 = reinterpret_cast<const float4*>(wxw + (size_t)y2 * X_N);
            float d1 = 0.f, d2 = 0.f;
            #pragma unroll
            for (int j = 0; j < 4; ++j) {
                float4 a1 = w1[j * 64 + lane];
                float4 a2 = w2[j * 64 + lane];
                d1 += xv[j].x*a1.x + xv[j].y*a1.y + xv[j].z*a1.z + xv[j].w*a1.w;
                d2 += xv[j].x*a2.x + xv[j].y*a2.y + xv[j].z*a2.z + xv[j].w*a2.w;
            }
            #pragma unroll
            for (int s = 32; s > 0; s >>= 1) {
                d1 += __shfl_xor(d1, s, 64);
                d2 += __shfl_xor(d2, s, 64);
            }
            float v1 = 0.5f*invx*inv_wx[y1]*d1 + 0.5f*inv_wz[y1]*wzw[(size_t)y1*Z_N + zb];
            unsigned long long p1 = pack_vi(v1, y1);
            bB = (p1 > bB) ? p1 : bB;
            if (h2) {
                float v2 = 0.5f*invx*inv_wx[y2]*d2 + 0.5f*inv_wz[y2]*wzw[(size_t)y2*Z_N + zb];
                unsigned long long p2 = pack_vi(v2, y2);
                bB = (p2 > bB) ? p2 : bB;
            }
        }
        if (lane == 0) red[wid] = bB;
    }
    __syncthreads();
    if (t == 0) {
        unsigned long long pm = sPM;
        unsigned enc = (unsigned)(pm >> 32);
        int idx = (int)(0xFFFFFFFFu - (unsigned)(pm & 0xFFFFFFFFull));
        int fin;
        if (sTakeA) {
            fin = idx;
        } else if (nB > 0) {
            unsigned long long pf = red[0];
            #pragma unroll
            for (int j = 1; j < 4; ++j) pf = (red[j] > pf) ? red[j] : pf;
            fin = (int)(0xFFFFFFFFu - (unsigned)(pf & 0xFFFFFFFFull));
        } else {
            fin = ctr[2];   // all-unact-nonpositive: ref argmax lands on first activated
        }
        final_idx[b] = fin;
        atomicAdd(&cnt[fin], 1);
        atomicMin(&segmin[fin], enc);
        atomicAdd(&zcnt[zb], 1);
    }
}

__global__ void wx_out_kernel(const float* __restrict__ wxw, const float* __restrict__ inv_wx,
                              const float* __restrict__ x, const float* __restrict__ inv_x,
                              const int* __restrict__ final_idx, const int* __restrict__ cnt,
                              const float* __restrict__ y_age, float* __restrict__ outw) {
    int j = blockIdx.x;
    int t = threadIdx.x;
    __shared__ int s_b[1024];
    __shared__ int s_n;
    if (t == 0) s_n = 0;
    __syncthreads();
    int c = cnt[j];
    if (c > 0) {
        for (int b = t; b < B_N; b += 256)
            if (final_idx[b] == j) { int p = atomicAdd(&s_n, 1); s_b[p] = b; }
    }
    __syncthreads();
    float inv = inv_wx[j];
    float lr = 1.0f / (y_age[j] + 1.0f);
    float fc = (float)c;
    float dv = (c > 0) ? fc : 1.0f;
    int n = s_n;
    float4 w = *reinterpret_cast<const float4*>(wxw + (size_t)j * X_N + t * 4);
    float4 wn = make_float4(w.x*inv, w.y*inv, w.z*inv, w.w*inv);
    if (c > 0) {
        float4 s = make_float4(0.f, 0.f, 0.f, 0.f);
        for (int m = 0; m < n; ++m) {
            int b = s_b[m];
            float ix = inv_x[b];
            float4 xv = *reinterpret_cast<const float4*>(x + (size_t)b * X_N + t * 4);
            s.x += xv.x * ix; s.y += xv.y * ix; s.z += xv.z * ix; s.w += xv.w * ix;
        }
        float f = lr / dv;
        wn.x += f * (s.x - fc * wn.x);
        wn.y += f * (s.y - fc * wn.y);
        wn.z += f * (s.z - fc * wn.z);
        wn.w += f * (s.w - fc * wn.w);
    }
    *reinterpret_cast<float4*>(outw + (size_t)j * X_N + t * 4) = wn;
}

__global__ void wz_out_kernel(const float* __restrict__ wzw, const float* __restrict__ inv_wz,
                              const int* __restrict__ zlab, const int* __restrict__ final_idx,
                              const int* __restrict__ cnt, const float* __restrict__ y_age,
                              float* __restrict__ outw) {
    int j = blockIdx.x;
    int t = threadIdx.x;
    __shared__ int s_c[1024];
    __shared__ int s_n;
    if (t == 0) s_n = 0;
    __syncthreads();
    int c = cnt[j];
    if (c > 0) {
        for (int b = t; b < B_N; b += 256)
            if (final_idx[b] == j) { int p = atomicAdd(&s_n, 1); s_c[p] = zlab[b]; }
    }
    __syncthreads();
    if (t >= 250) return;
    float inv = inv_wz[j];
    float lr = 1.0f / (y_age[j] + 1.0f);
    float fc = (float)c;
    float dv = (c > 0) ? fc : 1.0f;
    int n = s_n;
    float4 w = *reinterpret_cast<const float4*>(wzw + (size_t)j * Z_N + t * 4);
    float4 wn = make_float4(w.x*inv, w.y*inv, w.z*inv, w.w*inv);
    if (c > 0) {
        float4 s = make_float4(0.f, 0.f, 0.f, 0.f);
        for (int m = 0; m < n; ++m) {
            int d = s_c[m] - t * 4;
            if (d == 0) s.x += 1.f;
            else if (d == 1) s.y += 1.f;
            else if (d == 2) s.z += 1.f;
            else if (d == 3) s.w += 1.f;
        }
        float f = lr / dv;
        wn.x += f * (s.x - fc * wn.x);
        wn.y += f * (s.y - fc * wn.y);
        wn.z += f * (s.z - fc * wn.z);
        wn.w += f * (s.w - fc * wn.w);
    }
    *reinterpret_cast<float4*>(outw + (size_t)j * Z_N + t * 4) = wn;
}

__global__ void u_out_kernel(const float* __restrict__ uw, const float* __restrict__ inv_u,
                             const int* __restrict__ zlab, const int* __restrict__ final_idx,
                             const int* __restrict__ zcnt, const float* __restrict__ z_age,
                             float* __restrict__ outw) {
    int cz = blockIdx.x;
    int t = threadIdx.x;
    __shared__ int s_w[1024];
    __shared__ int s_n;
    if (t == 0) s_n = 0;
    __syncthreads();
    int c = zcnt[cz];
    if (c > 0) {
        for (int b = t; b < B_N; b += 256)
            if (zlab[b] == cz) { int p = atomicAdd(&s_n, 1); s_w[p] = final_idx[b]; }
    }
    __syncthreads();
    float inv = inv_u[cz];
    float zlr = 1.0f / (z_age[cz] + 1.0f);
    float fc = (float)c;
    float dv = (c > 0) ? fc : 1.0f;
    float f = zlr / dv;
    int n = s_n;
    const float* rowp = uw + (size_t)cz * Y_N;
    float* outp = outw + (size_t)cz * Y_N;
    for (int pass = 0; pass < 16; ++pass) {
        int e4 = pass * 256 + t;
        float4 u = *reinterpret_cast<const float4*>(rowp + e4 * 4);
        float4 un = make_float4(u.x*inv, u.y*inv, u.z*inv, u.w*inv);
        if (c > 0) {
            float4 s = make_float4(0.f, 0.f, 0.f, 0.f);
            for (int m = 0; m < n; ++m) {
                int d = s_w[m] - e4 * 4;
                if (d == 0) s.x += 1.f;
                else if (d == 1) s.y += 1.f;
                else if (d == 2) s.z += 1.f;
                else if (d == 3) s.w += 1.f;
            }
            un.x += f * (s.x - fc * un.x);
            un.y += f * (s.y - fc * un.y);
            un.z += f * (s.z - fc * un.z);
            un.w += f * (s.w - fc * un.w);
        }
        *reinterpret_cast<float4*>(outp + e4 * 4) = un;
    }
}

__global__ void thr_age_kernel(const int* __restrict__ cnt, const unsigned* __restrict__ segmin,
                               const float* __restrict__ y_age, const float* __restrict__ y_thr,
                               float* __restrict__ out_thr, float* __restrict__ out_age,
                               int* ctr) {
    int j = blockIdx.x * 256 + threadIdx.x;
    int c = cnt[j];
    float age = y_age[j];
    float thr = y_thr[j];
    float tn = thr;
    if (c > 0) {
        float lr = 1.0f / (age + 1.0f);
        float smin = dec_f(segmin[j]);
        float ycur = fminf(smin, 3.0f);
        if (ycur > 2.0f) ycur = 0.0f;
        tn = lr * ycur + (1.0f - lr) * thr;
    }
    out_thr[j] = tn;
    float an = age + (float)c;
    out_age[j] = an;
    unsigned long long m = __ballot(an >= 1.0f ? 1 : 0);
    if ((threadIdx.x & 63) == 0) atomicAdd(ctr + 1, (int)__popcll(m));
}

__global__ void zage_act_kernel(const int* __restrict__ zcnt, const float* __restrict__ z_age,
                                const int* __restrict__ ctr, float* __restrict__ out_zage,
                                float* __restrict__ out_act) {
    int i = blockIdx.x * 256 + threadIdx.x;
    if (i < Z_N) out_zage[i] = z_age[i] + (float)zcnt[i];
    if (i == 0) out_act[0] = (float)ctr[1];
}

extern "C" void kernel_launch(void* const* d_in, const int* in_sizes, int n_in,
                              void* d_out, int out_size, void* d_ws, size_t ws_size,
                              hipStream_t stream) {
    const float* x     = (const float*)d_in[0];
    const int*   z     = (const int*)d_in[1];
    const float* wxw   = (const float*)d_in[2];
    const float* wzw   = (const float*)d_in[3];
    const float* uw    = (const float*)d_in[4];
    const float* y_age = (const float*)d_in[5];
    const float* z_age = (const float*)d_in[6];
    const float* y_thr = (const float*)d_in[7];
    float* out = (float*)d_out;
    float* ws  = (float*)d_ws;
    char*  ob  = (char*)d_out;

    float* inv_x  = ws + WS_INV_X;
    float* inv_wx = ws + WS_INV_WX;
    float* inv_wz = ws + WS_INV_WZ;
    float* inv_u  = ws + WS_INV_U;
    int* fidx = (int*)(ws + WS_FIDX);
    int* cnt  = (int*)(ws + WS_CNT);
    int* zcnt = (int*)(ws + WS_ZCNT);
    unsigned* segmin = (unsigned*)(ws + WS_SEGMIN);
    int* ctr = (int*)(ws + WS_CTR);
    unsigned long long* mbits = (unsigned long long*)(ws + WS_MBITS);
    int* ccnt = (int*)(ws + WS_CCNT);

    ushort_t* Bb = (ushort_t*)(ob + SCR_B_BYTES);
    ushort_t* Sc = (ushort_t*)(ob + SCR_S_BYTES);
    ushort_t* Ab = (ushort_t*)(ob + SCR_A_BYTES);
    unsigned* gcand = (unsigned*)(ob + SCR_CAND_BYTES);

    init_kernel<<<64, 256, 0, stream>>>(cnt, segmin, zcnt, ctr);
    rownorm_kernel<<<B_N, 256, 0, stream>>>(x, X_N, inv_x);
    rownorm_kernel<<<Z_N, 256, 0, stream>>>(uw, Y_N, inv_u);
    unact_kernel<<<Y_N / 256, 256, 0, stream>>>(y_age, ctr, mbits);
    pack_x_kernel<<<(B_N * GK / 8) / 256, 256, 0, stream>>>(x, inv_x, z, Ab);
    pack_w_kernel<<<Y_N, 256, 0, stream>>>(wxw, wzw, Bb, inv_wx, inv_wz);
    mm256_kernel<<<(B_N / 256) * (Y_N / 256), 512, 0, stream>>>(Ab, Bb, Sc);
    scan_kernel<<<B_N, 256, 0, stream>>>(Sc, mbits, ctr, gcand, ccnt);
    rescore_kernel<<<B_N, 256, 0, stream>>>(gcand, ccnt, x, inv_x, wxw, inv_wx, wzw, inv_wz,
                                            z, y_thr, y_age, ctr, fidx, cnt, segmin, zcnt,
                                            out + OFF_MAXRESP);
    wx_out_kernel<<<Y_N, 256, 0, stream>>>(wxw, inv_wx, x, inv_x, fidx, cnt, y_age, out + OFF_WX);
    wz_out_kernel<<<Y_N, 256, 0, stream>>>(wzw, inv_wz, z, fidx, cnt, y_age, out + OFF_WZ);
    u_out_kernel<<<Z_N, 256, 0, stream>>>(uw, inv_u, z, fidx, zcnt, z_age, out + OFF_U);
    thr_age_kernel<<<Y_N / 256, 256, 0, stream>>>(cnt, segmin, y_age, y_thr,
                                                  out + OFF_THR, out + OFF_AGE, ctr);
    zage_act_kernel<<<4, 256, 0, stream>>>(zcnt, z_age, ctr, out + OFF_ZAGE, out + OFF_ACT);
}